// Round 1
// baseline (4004.053 us; speedup 1.0000x reference)
//
#include <hip/hip_runtime.h>
#include <math.h>

#define B_     128
#define DIM_   512
#define HEADS_ 8
#define HD_    64
#define N_     196
#define NOFF_  196
#define SCALE_ 0.125f

// LDS layout (floats) for hf_qkv_attn:
//   qk : [128][196]  q rows 0-63, k rows 64-127           (25088)
//   vt : [196][64]   v transposed, XOR bank-swizzled      (12544)
//   un : union { x stage [16][196] (3136) | P [4w][4][196] (3136) }
// total 40768 floats = 163072 B  (<= 163840 B LDS/CU)
#define QK_F   (128 * N_)
#define VT_F   (N_ * 64)
#define UN_F   (16 * N_)
#define LDS_F  (QK_F + VT_F + UN_F)
#define LDS_BYTES (LDS_F * 4)

__global__ __launch_bounds__(256) void hf_qkv_attn(
    const float* __restrict__ x,
    const float* __restrict__ qkv_w,
    const float* __restrict__ qkv_b,
    const float* __restrict__ biases,
    const int*   __restrict__ bidx,
    float*       __restrict__ attn_out)
{
    extern __shared__ float lds[];
    float* qk = lds;                 // q rows 0..63, k rows 64..127, row-major [r][196]
    float* vt = lds + QK_F;          // v transposed [m][64], column index XOR-swizzled
    float* un = lds + QK_F + VT_F;   // staging / P union
    float4* xs4 = reinterpret_cast<float4*>(un);

    const int t    = threadIdx.x;
    const int wave = t >> 6;
    const int lane = t & 63;
    const int b = blockIdx.x;
    const int h = blockIdx.y;
    const float* xb = x + (size_t)b * (DIM_ * N_);
    const int n0 = 4 * lane;                  // this lane's 4 n (or m) columns
    const int lc = (lane <= 48) ? lane : 48;  // clamp for loads; stores guarded
    const bool nok = (lane <= 48);            // n0 <= 192 -> all 4 columns valid

    // ---------------- phase 1: qkv rows for this head -------------------
    // Each wave: 8 rows x (4*lane..4*lane+3) n-columns, K chunked by 16 channels.
    float4 pf[4];
    {
        const float4* src = reinterpret_cast<const float4*>(xb);
        #pragma unroll
        for (int i = 0; i < 4; ++i) {
            int e = t + 256 * i;
            pf[i] = (e < 784) ? src[e] : make_float4(0.f, 0.f, 0.f, 0.f);
        }
    }
    for (int rg = 0; rg < 6; ++rg) {
        const int r0   = rg * 32 + wave * 8;      // local row 0..184, multiple of 8
        const int part = r0 >> 6;                 // 0=q 1=k 2=v (no straddle)
        const int grow0 = __builtin_amdgcn_readfirstlane(part * DIM_ + h * HD_ + (r0 & 63));
        float4 acc[8];
        #pragma unroll
        for (int jr = 0; jr < 8; ++jr) acc[jr] = make_float4(0.f, 0.f, 0.f, 0.f);

        for (int c0 = 0; c0 < DIM_; c0 += 16) {
            __syncthreads();
            #pragma unroll
            for (int i = 0; i < 4; ++i) {         // commit prefetched chunk to LDS
                int e = t + 256 * i;
                if (e < 784) xs4[e] = pf[i];
            }
            {                                     // prefetch next chunk (wraps per rg)
                const int cn = (c0 + 16) & (DIM_ - 1);
                const float4* src = reinterpret_cast<const float4*>(xb + (size_t)cn * N_);
                #pragma unroll
                for (int i = 0; i < 4; ++i) {
                    int e = t + 256 * i;
                    if (e < 784) pf[i] = src[e];
                }
            }
            __syncthreads();
            const float* wp = qkv_w + (size_t)grow0 * DIM_ + c0;  // uniform -> s_load
            #pragma unroll
            for (int cc = 0; cc < 16; ++cc) {
                const float4 xv = xs4[cc * 49 + lc];
                #pragma unroll
                for (int jr = 0; jr < 8; ++jr) {
                    const float wv = wp[jr * DIM_ + cc];
                    acc[jr].x = fmaf(wv, xv.x, acc[jr].x);
                    acc[jr].y = fmaf(wv, xv.y, acc[jr].y);
                    acc[jr].z = fmaf(wv, xv.z, acc[jr].z);
                    acc[jr].w = fmaf(wv, xv.w, acc[jr].w);
                }
            }
        }
        if (nok) {
            if (part < 2) {                       // q,k: row-major, b128 stores
                #pragma unroll
                for (int jr = 0; jr < 8; ++jr) {
                    const float bb = qkv_b[grow0 + jr];
                    float4 v = acc[jr];
                    v.x += bb; v.y += bb; v.z += bb; v.w += bb;
                    *reinterpret_cast<float4*>(&qk[(r0 + jr) * N_ + n0]) = v;
                }
            } else {                              // v: transposed + swizzle (8-way store, read-free)
                #pragma unroll
                for (int jr = 0; jr < 8; ++jr) {
                    const float bb = qkv_b[grow0 + jr];
                    const int dc = r0 - 128 + jr;
                    const float* av = reinterpret_cast<const float*>(&acc[jr]);
                    #pragma unroll
                    for (int j = 0; j < 4; ++j) {
                        const int m = n0 + j;
                        vt[m * 64 + (dc ^ (m & 31))] = av[j] + bb;
                    }
                }
            }
        }
    }
    __syncthreads();

    // ---------------- phase 2: attention (per wave: 49 query rows) -------
    const float* k_l = qk + 64 * N_;
    float* pw = un + wave * (4 * N_);             // this wave's P rows [4][196]
    const int mc = (n0 <= 192) ? n0 : 192;        // clamped m base for loads
    const float* bh = biases + h * NOFF_;

    for (int g = 0; g < 13; ++g) {
        const int nvalid = (g == 12) ? 1 : 4;     // 49 = 12*4 + 1
        const int nb = 49 * wave + 4 * g;
        int ncol[4];
        #pragma unroll
        for (int jn = 0; jn < 4; ++jn) ncol[jn] = nb + ((jn < nvalid) ? jn : 0);

        // S[n, m] = sum_d q[d,n] * k[d,m]
        float4 s4[4];
        #pragma unroll
        for (int jn = 0; jn < 4; ++jn) s4[jn] = make_float4(0.f, 0.f, 0.f, 0.f);
        for (int d = 0; d < 64; ++d) {
            const float4 kv = *reinterpret_cast<const float4*>(&k_l[d * N_ + mc]);
            #pragma unroll
            for (int jn = 0; jn < 4; ++jn) {
                const float qv = qk[d * N_ + ncol[jn]];
                s4[jn].x = fmaf(qv, kv.x, s4[jn].x);
                s4[jn].y = fmaf(qv, kv.y, s4[jn].y);
                s4[jn].z = fmaf(qv, kv.z, s4[jn].z);
                s4[jn].w = fmaf(qv, kv.w, s4[jn].w);
            }
        }
        // scale + bias + softmax, write P
        #pragma unroll
        for (int jn = 0; jn < 4; ++jn) {
            if (jn >= nvalid) continue;           // wave-uniform
            const int n = nb + jn;
            const int4 iv = *reinterpret_cast<const int4*>(&bidx[n * N_ + mc]);
            const int* ivp = reinterpret_cast<const int*>(&iv);
            const float* sp = reinterpret_cast<const float*>(&s4[jn]);
            float sv[4];
            float mx = -INFINITY;
            #pragma unroll
            for (int jj = 0; jj < 4; ++jj) {
                const float vv = nok ? fmaf(sp[jj], SCALE_, bh[ivp[jj]]) : -INFINITY;
                sv[jj] = vv;
                mx = fmaxf(mx, vv);
            }
            for (int off = 1; off < 64; off <<= 1)
                mx = fmaxf(mx, __shfl_xor(mx, off, 64));
            float sum = 0.f;
            #pragma unroll
            for (int jj = 0; jj < 4; ++jj) {
                const float e = __expf(sv[jj] - mx);   // -inf -> 0 for masked lanes
                sv[jj] = e;
                sum += e;
            }
            for (int off = 1; off < 64; off <<= 1)
                sum += __shfl_xor(sum, off, 64);
            const float inv = 1.f / sum;
            if (nok) {
                *reinterpret_cast<float4*>(&pw[jn * N_ + mc]) =
                    make_float4(sv[0] * inv, sv[1] * inv, sv[2] * inv, sv[3] * inv);
            }
        }
        // O[d, n] = sum_m P[n,m] v[d,m]   (lane = d)
        float4 ov = make_float4(0.f, 0.f, 0.f, 0.f);
        for (int m0 = 0; m0 < N_; m0 += 4) {
            const float4 p0 = *reinterpret_cast<const float4*>(&pw[0 * N_ + m0]);
            const float4 p1 = *reinterpret_cast<const float4*>(&pw[1 * N_ + m0]);
            const float4 p2 = *reinterpret_cast<const float4*>(&pw[2 * N_ + m0]);
            const float4 p3 = *reinterpret_cast<const float4*>(&pw[3 * N_ + m0]);
            const float* a0 = reinterpret_cast<const float*>(&p0);
            const float* a1 = reinterpret_cast<const float*>(&p1);
            const float* a2 = reinterpret_cast<const float*>(&p2);
            const float* a3 = reinterpret_cast<const float*>(&p3);
            #pragma unroll
            for (int mm = 0; mm < 4; ++mm) {
                const int m = m0 + mm;
                const float vv = vt[m * 64 + (lane ^ (m & 31))];
                ov.x = fmaf(a0[mm], vv, ov.x);
                ov.y = fmaf(a1[mm], vv, ov.y);
                ov.z = fmaf(a2[mm], vv, ov.z);
                ov.w = fmaf(a3[mm], vv, ov.w);
            }
        }
        {   // write O into the q area (columns owned exclusively by this wave)
            const float* op = reinterpret_cast<const float*>(&ov);
            #pragma unroll
            for (int jn = 0; jn < 4; ++jn)
                if (jn < nvalid) qk[lane * N_ + nb + jn] = op[jn];
        }
    }
    __syncthreads();
    {   // coalesced block copy of the 64x196 head output
        float4* dst = reinterpret_cast<float4*>(attn_out + ((size_t)b * DIM_ + (size_t)h * HD_) * N_);
        const float4* src = reinterpret_cast<const float4*>(qk);
        for (int e = t; e < (HD_ * N_) / 4; e += 256) dst[e] = src[e];
    }
}

__global__ __launch_bounds__(256) void hf_proj(
    const float* __restrict__ attn,
    const float* __restrict__ proj_w,
    const float* __restrict__ proj_b,
    float*       __restrict__ out)
{
    __shared__ float xs[UN_F];
    float4* xs4 = reinterpret_cast<float4*>(xs);
    const int t = threadIdx.x;
    const int wave = t >> 6;
    const int lane = t & 63;
    const int b = blockIdx.x;
    const int tile = blockIdx.y;        // 8 tiles x 64 rows
    const float* ab = attn + (size_t)b * (DIM_ * N_);
    float* ob = out + (size_t)b * (DIM_ * N_);
    const int n0 = 4 * lane;
    const int lc = (lane <= 48) ? lane : 48;
    const bool nok = (lane <= 48);

    float4 pf[4];
    {
        const float4* src = reinterpret_cast<const float4*>(ab);
        #pragma unroll
        for (int i = 0; i < 4; ++i) {
            int e = t + 256 * i;
            pf[i] = (e < 784) ? src[e] : make_float4(0.f, 0.f, 0.f, 0.f);
        }
    }
    for (int rg = 0; rg < 2; ++rg) {
        const int r0 = tile * 64 + rg * 32 + wave * 8;
        const int grow0 = __builtin_amdgcn_readfirstlane(r0);
        float4 acc[8];
        #pragma unroll
        for (int jr = 0; jr < 8; ++jr) acc[jr] = make_float4(0.f, 0.f, 0.f, 0.f);

        for (int c0 = 0; c0 < DIM_; c0 += 16) {
            __syncthreads();
            #pragma unroll
            for (int i = 0; i < 4; ++i) {
                int e = t + 256 * i;
                if (e < 784) xs4[e] = pf[i];
            }
            {
                const int cn = (c0 + 16) & (DIM_ - 1);
                const float4* src = reinterpret_cast<const float4*>(ab + (size_t)cn * N_);
                #pragma unroll
                for (int i = 0; i < 4; ++i) {
                    int e = t + 256 * i;
                    if (e < 784) pf[i] = src[e];
                }
            }
            __syncthreads();
            const float* wp = proj_w + (size_t)grow0 * DIM_ + c0;
            #pragma unroll
            for (int cc = 0; cc < 16; ++cc) {
                const float4 xv = xs4[cc * 49 + lc];
                #pragma unroll
                for (int jr = 0; jr < 8; ++jr) {
                    const float wv = wp[jr * DIM_ + cc];
                    acc[jr].x = fmaf(wv, xv.x, acc[jr].x);
                    acc[jr].y = fmaf(wv, xv.y, acc[jr].y);
                    acc[jr].z = fmaf(wv, xv.z, acc[jr].z);
                    acc[jr].w = fmaf(wv, xv.w, acc[jr].w);
                }
            }
        }
        if (nok) {
            #pragma unroll
            for (int jr = 0; jr < 8; ++jr) {
                const float bb = proj_b[grow0 + jr];
                float4 v = acc[jr];
                v.x += bb; v.y += bb; v.z += bb; v.w += bb;
                *reinterpret_cast<float4*>(&ob[(size_t)(r0 + jr) * N_ + n0]) = v;
            }
        }
    }
}

extern "C" void kernel_launch(void* const* d_in, const int* in_sizes, int n_in,
                              void* d_out, int out_size, void* d_ws, size_t ws_size,
                              hipStream_t stream) {
    const float* x      = (const float*)d_in[0];
    const float* qkv_w  = (const float*)d_in[1];
    const float* qkv_b  = (const float*)d_in[2];
    const float* proj_w = (const float*)d_in[3];
    const float* proj_b = (const float*)d_in[4];
    const float* biases = (const float*)d_in[5];
    const int*   bidx   = (const int*)d_in[6];
    float* attn = (float*)d_ws;            // 128*512*196 fp32 = 51.4 MB scratch
    float* out  = (float*)d_out;

    // Allow >64 KB dynamic LDS (capture-safe: not a stream op; ignore errors).
    (void)hipFuncSetAttribute(reinterpret_cast<const void*>(hf_qkv_attn),
                              hipFuncAttributeMaxDynamicSharedMemorySize, LDS_BYTES);

    hf_qkv_attn<<<dim3(B_, HEADS_), 256, LDS_BYTES, stream>>>(x, qkv_w, qkv_b, biases, bidx, attn);
    hf_proj<<<dim3(B_, 8), 256, 0, stream>>>(attn, proj_w, proj_b, out);
}

// Round 2
// 2364.680 us; speedup vs baseline: 1.6933x; 1.6933x over previous
//
#include <hip/hip_runtime.h>
#include <math.h>

#define B_     128
#define DIM_   512
#define HEADS_ 8
#define HD_    64
#define N_     196
#define SCALE_ 0.125f
#define BSTRIDE (DIM_ * N_)   // 100352 floats: per-batch stride of every 512x196 buffer

__device__ __forceinline__ float rdlane(float v, int l) {
    return __int_as_float(__builtin_amdgcn_readlane(__float_as_int(v), l));
}

// ---------------------------------------------------------------------------
// Row-tiled GEMM: out[r][n] = sum_c w[r][c]*in[c][n] + bias[r], n in [0,196).
// grid=(B, Mtiles); block=256. Block computes 64 rows (wave: 16 rows, lane: 4 n).
// Output pointer selected per 512-row part (q/k/v for the qkv GEMM).
// LDS = 12.5 KB only -> ~4 blocks/CU; weights via uniform s_loads.
// ---------------------------------------------------------------------------
__global__ __launch_bounds__(256, 4) void gemm64(
    const float* __restrict__ in, const float* __restrict__ w,
    const float* __restrict__ bias,
    float* __restrict__ out0, float* __restrict__ out1, float* __restrict__ out2)
{
    __shared__ float4 xs4[16 * 49];            // 16 channels x 196 floats
    const int t = threadIdx.x;
    const int wave = t >> 6, lane = t & 63;
    const int b = blockIdx.x, ty = blockIdx.y;
    const float* inb = in + (size_t)b * BSTRIDE;
    const int n0 = 4 * lane;
    const int lc = (lane <= 48) ? lane : 48;   // clamp loads; stores guarded
    const bool nok = (lane <= 48);
    const int o0 = __builtin_amdgcn_readfirstlane(ty * 64 + wave * 16);

    float4 pf[4];
    {
        const float4* src = reinterpret_cast<const float4*>(inb);
        #pragma unroll
        for (int i = 0; i < 4; ++i) { int e = t + 256 * i; pf[i] = (e < 784) ? src[e] : make_float4(0.f,0.f,0.f,0.f); }
    }
    float4 acc[16];
    #pragma unroll
    for (int j = 0; j < 16; ++j) acc[j] = make_float4(0.f, 0.f, 0.f, 0.f);

    for (int c0 = 0; c0 < DIM_; c0 += 16) {
        __syncthreads();
        #pragma unroll
        for (int i = 0; i < 4; ++i) { int e = t + 256 * i; if (e < 784) xs4[e] = pf[i]; }
        {   // prefetch next 16-channel slab (wraps harmlessly on the last iter)
            const int cn = (c0 + 16) & (DIM_ - 1);
            const float4* src = reinterpret_cast<const float4*>(inb + (size_t)cn * N_);
            #pragma unroll
            for (int i = 0; i < 4; ++i) { int e = t + 256 * i; if (e < 784) pf[i] = src[e]; }
        }
        __syncthreads();
        const float* wp = w + (size_t)o0 * DIM_ + c0;   // uniform -> s_load
        #pragma unroll
        for (int cc = 0; cc < 16; ++cc) {
            const float4 xv = xs4[cc * 49 + lc];
            #pragma unroll
            for (int j = 0; j < 16; ++j) {
                const float wv = wp[j * DIM_ + cc];
                acc[j].x = fmaf(wv, xv.x, acc[j].x);
                acc[j].y = fmaf(wv, xv.y, acc[j].y);
                acc[j].z = fmaf(wv, xv.z, acc[j].z);
                acc[j].w = fmaf(wv, xv.w, acc[j].w);
            }
        }
    }
    float* outs[3] = {out0, out1, out2};
    float* ob = outs[ty >> 3] + (size_t)b * BSTRIDE;
    if (nok) {
        #pragma unroll
        for (int j = 0; j < 16; ++j) {
            const int o = o0 + j;
            const float bb = bias[o];
            float4 v = acc[j];
            v.x += bb; v.y += bb; v.z += bb; v.w += bb;
            *reinterpret_cast<float4*>(&ob[(size_t)(o & (DIM_ - 1)) * N_ + n0]) = v;
        }
    }
}

// ---------------------------------------------------------------------------
// Attention per (b,h): S=q^T k*scale+bias -> softmax -> O=v P^T.
// 1024 threads (16 waves). LDS = k[64][196] + v^T[196][64] (100 KB) only:
// q broadcast via v_readlane from per-lane registers (lane = d), P broadcast
// via v_readlane from owner lanes (lane = m/4). O kept in VGPRs, transposed
// through the (dead) k LDS at the end for a coalesced store into the q region.
// ---------------------------------------------------------------------------
__global__ __launch_bounds__(1024, 4) void attn196(
    const float* __restrict__ qg, const float* __restrict__ kg,
    const float* __restrict__ vg, const float* __restrict__ biases,
    const int*   __restrict__ bidx, float* __restrict__ og)
{
    extern __shared__ float lds2[];
    float* ksh = lds2;             // k [d][196]; reused as O [d][196] at the end
    float* vt  = lds2 + HD_ * N_;  // v^T [m][64], xor bank swizzle
    const int t = threadIdx.x;
    const int wave = t >> 6, lane = t & 63;
    const int b = blockIdx.x, h = blockIdx.y;
    const size_t hb = ((size_t)b * DIM_ + (size_t)h * HD_) * N_;

    {   // stage k (direct) and v (transpose+swizzle), coalesced float4 reads
        const float4* ks = reinterpret_cast<const float4*>(kg + hb);
        float4* kd = reinterpret_cast<float4*>(ksh);
        for (int e = t; e < 3136; e += 1024) kd[e] = ks[e];
        const float4* vs = reinterpret_cast<const float4*>(vg + hb);
        for (int e = t; e < 3136; e += 1024) {
            const float4 vv = vs[e];
            const int d = e / 49, m0 = 4 * (e % 49);
            const float* vvp = reinterpret_cast<const float*>(&vv);
            #pragma unroll
            for (int i = 0; i < 4; ++i) {
                const int m = m0 + i;
                vt[m * HD_ + (d ^ (m & 31))] = vvp[i];
            }
        }
    }
    __syncthreads();

    const int start = (wave < 4) ? 13 * wave : 52 + 12 * (wave - 4);
    const int nrows = (wave < 4) ? 13 : 12;
    const int G = (nrows + 3) >> 2;
    const int mc = (lane <= 48) ? 4 * lane : 192;   // clamped m base (4 m's)
    const bool mok = (lane <= 48);
    const float* bh = biases + h * N_;
    const float* qp = qg + hb + (size_t)lane * N_;  // q row d = lane

    float oacc[4][4];
    #pragma unroll
    for (int g = 0; g < 4; ++g)
        #pragma unroll
        for (int j = 0; j < 4; ++j) oacc[g][j] = 0.f;

    #pragma unroll
    for (int g = 0; g < 4; ++g) {
        if (g < G) {
            const int nvalid = (nrows - 4 * g >= 4) ? 4 : (nrows - 4 * g);
            int ncol[4];
            #pragma unroll
            for (int jn = 0; jn < 4; ++jn) ncol[jn] = start + 4 * g + ((jn < nvalid) ? jn : 0);
            float q4[4];
            #pragma unroll
            for (int jn = 0; jn < 4; ++jn) q4[jn] = qp[ncol[jn]];  // uncoalesced gather, L2-hot

            // S[n][m]: lane owns 4 m; q[d][n] broadcast via readlane (SALU)
            float4 s4[4];
            #pragma unroll
            for (int jn = 0; jn < 4; ++jn) s4[jn] = make_float4(0.f, 0.f, 0.f, 0.f);
            #pragma unroll 4
            for (int d = 0; d < 64; ++d) {
                const float4 kv = *reinterpret_cast<const float4*>(&ksh[d * N_ + mc]);
                #pragma unroll
                for (int jn = 0; jn < 4; ++jn) {
                    const float qv = rdlane(q4[jn], d);
                    s4[jn].x = fmaf(qv, kv.x, s4[jn].x);
                    s4[jn].y = fmaf(qv, kv.y, s4[jn].y);
                    s4[jn].z = fmaf(qv, kv.z, s4[jn].z);
                    s4[jn].w = fmaf(qv, kv.w, s4[jn].w);
                }
            }
            // softmax rows (bias gather from L1-resident 784 B table)
            float pvA[4][4];
            #pragma unroll
            for (int jn = 0; jn < 4; ++jn) {
                const int4 iv = *reinterpret_cast<const int4*>(&bidx[(size_t)ncol[jn] * N_ + mc]);
                const int* ivp = reinterpret_cast<const int*>(&iv);
                const float* sp = reinterpret_cast<const float*>(&s4[jn]);
                float sv[4]; float mx = -INFINITY;
                #pragma unroll
                for (int jj = 0; jj < 4; ++jj) {
                    const float vv = mok ? fmaf(sp[jj], SCALE_, bh[ivp[jj]]) : -INFINITY;
                    sv[jj] = vv; mx = fmaxf(mx, vv);
                }
                #pragma unroll
                for (int off = 1; off < 64; off <<= 1) mx = fmaxf(mx, __shfl_xor(mx, off, 64));
                float sum = 0.f;
                #pragma unroll
                for (int jj = 0; jj < 4; ++jj) { const float e = __expf(sv[jj] - mx); sv[jj] = e; sum += e; }
                #pragma unroll
                for (int off = 1; off < 64; off <<= 1) sum += __shfl_xor(sum, off, 64);
                const float inv = 1.f / sum;
                #pragma unroll
                for (int jj = 0; jj < 4; ++jj) pvA[jn][jj] = sv[jj] * inv;
            }
            // O[d=lane][n] += sum_m P[n][m] v[d][m]; P broadcast via readlane
            for (int s = 0; s < 49; ++s) {
                const int m0 = 4 * s;
                float vvm[4];
                #pragma unroll
                for (int mm = 0; mm < 4; ++mm)
                    vvm[mm] = vt[(m0 + mm) * HD_ + (lane ^ ((m0 + mm) & 31))];
                #pragma unroll
                for (int jn = 0; jn < 4; ++jn)
                    #pragma unroll
                    for (int mm = 0; mm < 4; ++mm)
                        oacc[g][jn] = fmaf(rdlane(pvA[jn][mm], s), vvm[mm], oacc[g][jn]);
            }
        }
    }
    __syncthreads();                         // all waves done reading k
    #pragma unroll
    for (int g = 0; g < 4; ++g) {
        if (g < G) {
            const int nvalid = (nrows - 4 * g >= 4) ? 4 : (nrows - 4 * g);
            #pragma unroll
            for (int jn = 0; jn < 4; ++jn)
                if (jn < nvalid) ksh[lane * N_ + start + 4 * g + jn] = oacc[g][jn];
        }
    }
    __syncthreads();
    {   // coalesced store of O into the q region (this block's own q rows)
        float4* dst = reinterpret_cast<float4*>(og + hb);
        const float4* src = reinterpret_cast<const float4*>(ksh);
        for (int e = t; e < 3136; e += 1024) dst[e] = src[e];
    }
}

extern "C" void kernel_launch(void* const* d_in, const int* in_sizes, int n_in,
                              void* d_out, int out_size, void* d_ws, size_t ws_size,
                              hipStream_t stream) {
    const float* x      = (const float*)d_in[0];
    const float* qkv_w  = (const float*)d_in[1];
    const float* qkv_b  = (const float*)d_in[2];
    const float* proj_w = (const float*)d_in[3];
    const float* proj_b = (const float*)d_in[4];
    const float* biases = (const float*)d_in[5];
    const int*   bidx   = (const int*)d_in[6];
    float* out = (float*)d_out;

    // ws: q then v (51.4 MB each). k lives in d_out until proj overwrites it.
    float* qws = (float*)d_ws;
    float* vws = qws + (size_t)B_ * BSTRIDE;

    (void)hipFuncSetAttribute(reinterpret_cast<const void*>(attn196),
                              hipFuncAttributeMaxDynamicSharedMemorySize,
                              (HD_ * N_ + N_ * HD_) * 4);

    // qkv GEMM: 1536 rows -> q(ws) / k(d_out) / v(ws)
    gemm64<<<dim3(B_, 24), 256, 0, stream>>>(x, qkv_w, qkv_b, qws, out, vws);
    // attention: reads q/k/v, writes O back over the q region
    attn196<<<dim3(B_, HEADS_), 1024, (HD_ * N_ + N_ * HD_) * 4, stream>>>(
        qws, out, vws, biases, bidx, qws);
    // proj GEMM: 512 rows, reads attn (q region), writes final out
    gemm64<<<dim3(B_, 8), 256, 0, stream>>>(qws, proj_w, proj_b, out, out, out);
}

// Round 3
// 2022.809 us; speedup vs baseline: 1.9795x; 1.1690x over previous
//
#include <hip/hip_runtime.h>
#include <math.h>

#define B_     128
#define DIM_   512
#define HEADS_ 8
#define HD_    64
#define N_     196
#define SCALE_ 0.125f
#define BSTRIDE (DIM_ * N_)   // 100352 floats: per-batch stride of every 512x196 buffer

__device__ __forceinline__ float rdlane(float v, int l) {
    return __int_as_float(__builtin_amdgcn_readlane(__float_as_int(v), l));
}

// ---------------------------------------------------------------------------
// Row-tiled GEMM: out[r][n] = sum_c w[r][c]*in[c][n] + bias[r], n in [0,196).
// grid=(B, Mtiles); block=256. Block = 32 rows (wave: 8 rows, lane: 4 n).
// acc[8] = 32 VGPRs -> total demand ~60 regs -> 8 waves/EU, NO SPILL
// (round-2's 16-row tile demanded ~100 regs, compiler pinned 64, spilled:
//  WRITE_SIZE 1.26 GB vs 154 MB ideal. Never again.)
// ---------------------------------------------------------------------------
__global__ __attribute__((amdgpu_waves_per_eu(6, 8)))
__launch_bounds__(256) void gemm32(
    const float* __restrict__ in, const float* __restrict__ w,
    const float* __restrict__ bias,
    float* __restrict__ out0, float* __restrict__ out1, float* __restrict__ out2)
{
    __shared__ float4 xs4[16 * 49];            // 16 channels x 196 floats = 12.5 KB
    const int t = threadIdx.x;
    const int wave = t >> 6, lane = t & 63;
    const int b = blockIdx.x, ty = blockIdx.y;
    const float* inb = in + (size_t)b * BSTRIDE;
    const int n0 = 4 * lane;
    const int lc = (lane <= 48) ? lane : 48;   // clamp loads; stores guarded
    const bool nok = (lane <= 48);
    const int o0 = __builtin_amdgcn_readfirstlane(ty * 32 + wave * 8);  // global out row

    float4 pf[4];
    {
        const float4* src = reinterpret_cast<const float4*>(inb);
        #pragma unroll
        for (int i = 0; i < 4; ++i) { int e = t + 256 * i; pf[i] = (e < 784) ? src[e] : make_float4(0.f,0.f,0.f,0.f); }
    }
    float4 acc[8];
    #pragma unroll
    for (int j = 0; j < 8; ++j) acc[j] = make_float4(0.f, 0.f, 0.f, 0.f);

    for (int c0 = 0; c0 < DIM_; c0 += 16) {
        __syncthreads();
        #pragma unroll
        for (int i = 0; i < 4; ++i) { int e = t + 256 * i; if (e < 784) xs4[e] = pf[i]; }
        {   // prefetch next 16-channel slab (wraps harmlessly on the last iter)
            const int cn = (c0 + 16) & (DIM_ - 1);
            const float4* src = reinterpret_cast<const float4*>(inb + (size_t)cn * N_);
            #pragma unroll
            for (int i = 0; i < 4; ++i) { int e = t + 256 * i; if (e < 784) pf[i] = src[e]; }
        }
        __syncthreads();
        const float* wp = w + (size_t)o0 * DIM_ + c0;   // uniform -> s_load
        #pragma unroll
        for (int cc = 0; cc < 16; ++cc) {
            const float4 xv = xs4[cc * 49 + lc];
            #pragma unroll
            for (int j = 0; j < 8; ++j) {
                const float wv = wp[j * DIM_ + cc];
                acc[j].x = fmaf(wv, xv.x, acc[j].x);
                acc[j].y = fmaf(wv, xv.y, acc[j].y);
                acc[j].z = fmaf(wv, xv.z, acc[j].z);
                acc[j].w = fmaf(wv, xv.w, acc[j].w);
            }
        }
    }
    // uniform output-part select (no dynamic-indexed local array -> no scratch)
    float* obase = (o0 < 512) ? out0 : ((o0 < 1024) ? out1 : out2);
    float* ob = obase + (size_t)b * BSTRIDE;
    if (nok) {
        #pragma unroll
        for (int j = 0; j < 8; ++j) {
            const int o = o0 + j;
            const float bb = bias[o];
            float4 v = acc[j];
            v.x += bb; v.y += bb; v.z += bb; v.w += bb;
            *reinterpret_cast<float4*>(&ob[(size_t)(o & (DIM_ - 1)) * N_ + n0]) = v;
        }
    }
}

// ---------------------------------------------------------------------------
// Attention per (b,h): S=q^T k*scale+bias -> softmax -> O=v P^T.
// 1024 threads (16 waves). LDS = k[64][196] + v^T[196][64] (100 KB).
// q and P broadcast via v_readlane; O in VGPRs, transposed through the dead
// k LDS at the end. waves_per_eu(4,4): demand ~80 regs, pin cap at 128 so
// the backend can't target 8 waves/EU and spill.
// ---------------------------------------------------------------------------
__global__ __attribute__((amdgpu_waves_per_eu(4, 4)))
__launch_bounds__(1024) void attn196(
    const float* __restrict__ qg, const float* __restrict__ kg,
    const float* __restrict__ vg, const float* __restrict__ biases,
    const int*   __restrict__ bidx, float* __restrict__ og)
{
    extern __shared__ float lds2[];
    float* ksh = lds2;             // k [d][196]; reused as O [d][196] at the end
    float* vt  = lds2 + HD_ * N_;  // v^T [m][64], xor bank swizzle
    const int t = threadIdx.x;
    const int wave = t >> 6, lane = t & 63;
    const int b = blockIdx.x, h = blockIdx.y;
    const size_t hb = ((size_t)b * DIM_ + (size_t)h * HD_) * N_;

    {   // stage k (direct) and v (transpose+swizzle), coalesced float4 reads
        const float4* ks = reinterpret_cast<const float4*>(kg + hb);
        float4* kd = reinterpret_cast<float4*>(ksh);
        for (int e = t; e < 3136; e += 1024) kd[e] = ks[e];
        const float4* vs = reinterpret_cast<const float4*>(vg + hb);
        for (int e = t; e < 3136; e += 1024) {
            const float4 vv = vs[e];
            const int d = e / 49, m0 = 4 * (e % 49);
            const float* vvp = reinterpret_cast<const float*>(&vv);
            #pragma unroll
            for (int i = 0; i < 4; ++i) {
                const int m = m0 + i;
                vt[m * HD_ + (d ^ (m & 31))] = vvp[i];
            }
        }
    }
    __syncthreads();

    const int start = (wave < 4) ? 13 * wave : 52 + 12 * (wave - 4);
    const int nrows = (wave < 4) ? 13 : 12;
    const int G = (nrows + 3) >> 2;
    const int mc = (lane <= 48) ? 4 * lane : 192;   // clamped m base (4 m's)
    const bool mok = (lane <= 48);
    const float* bh = biases + h * N_;
    const float* qp = qg + hb + (size_t)lane * N_;  // q row d = lane

    float oacc[4][4];
    #pragma unroll
    for (int g = 0; g < 4; ++g)
        #pragma unroll
        for (int j = 0; j < 4; ++j) oacc[g][j] = 0.f;

    #pragma unroll
    for (int g = 0; g < 4; ++g) {
        if (g < G) {
            const int nvalid = (nrows - 4 * g >= 4) ? 4 : (nrows - 4 * g);
            int ncol[4];
            #pragma unroll
            for (int jn = 0; jn < 4; ++jn) ncol[jn] = start + 4 * g + ((jn < nvalid) ? jn : 0);
            float q4[4];
            #pragma unroll
            for (int jn = 0; jn < 4; ++jn) q4[jn] = qp[ncol[jn]];  // uncoalesced gather, L2-hot

            // S[n][m]: lane owns 4 m; q[d][n] broadcast via readlane (SALU)
            float4 s4[4];
            #pragma unroll
            for (int jn = 0; jn < 4; ++jn) s4[jn] = make_float4(0.f, 0.f, 0.f, 0.f);
            #pragma unroll 4
            for (int d = 0; d < 64; ++d) {
                const float4 kv = *reinterpret_cast<const float4*>(&ksh[d * N_ + mc]);
                #pragma unroll
                for (int jn = 0; jn < 4; ++jn) {
                    const float qv = rdlane(q4[jn], d);
                    s4[jn].x = fmaf(qv, kv.x, s4[jn].x);
                    s4[jn].y = fmaf(qv, kv.y, s4[jn].y);
                    s4[jn].z = fmaf(qv, kv.z, s4[jn].z);
                    s4[jn].w = fmaf(qv, kv.w, s4[jn].w);
                }
            }
            // softmax rows (bias gather from L1-resident 784 B table)
            float pvA[4][4];
            #pragma unroll
            for (int jn = 0; jn < 4; ++jn) {
                const int4 iv = *reinterpret_cast<const int4*>(&bidx[(size_t)ncol[jn] * N_ + mc]);
                const int* ivp = reinterpret_cast<const int*>(&iv);
                const float* sp = reinterpret_cast<const float*>(&s4[jn]);
                float sv[4]; float mx = -INFINITY;
                #pragma unroll
                for (int jj = 0; jj < 4; ++jj) {
                    const float vv = mok ? fmaf(sp[jj], SCALE_, bh[ivp[jj]]) : -INFINITY;
                    sv[jj] = vv; mx = fmaxf(mx, vv);
                }
                #pragma unroll
                for (int off = 1; off < 64; off <<= 1) mx = fmaxf(mx, __shfl_xor(mx, off, 64));
                float sum = 0.f;
                #pragma unroll
                for (int jj = 0; jj < 4; ++jj) { const float e = __expf(sv[jj] - mx); sv[jj] = e; sum += e; }
                #pragma unroll
                for (int off = 1; off < 64; off <<= 1) sum += __shfl_xor(sum, off, 64);
                const float inv = 1.f / sum;
                #pragma unroll
                for (int jj = 0; jj < 4; ++jj) pvA[jn][jj] = sv[jj] * inv;
            }
            // O[d=lane][n] += sum_m P[n][m] v[d][m]; P broadcast via readlane
            for (int s = 0; s < 49; ++s) {
                const int m0 = 4 * s;
                float vvm[4];
                #pragma unroll
                for (int mm = 0; mm < 4; ++mm)
                    vvm[mm] = vt[(m0 + mm) * HD_ + (lane ^ ((m0 + mm) & 31))];
                #pragma unroll
                for (int jn = 0; jn < 4; ++jn)
                    #pragma unroll
                    for (int mm = 0; mm < 4; ++mm)
                        oacc[g][jn] = fmaf(rdlane(pvA[jn][mm], s), vvm[mm], oacc[g][jn]);
            }
        }
    }
    __syncthreads();                         // all waves done reading k
    #pragma unroll
    for (int g = 0; g < 4; ++g) {
        if (g < G) {
            const int nvalid = (nrows - 4 * g >= 4) ? 4 : (nrows - 4 * g);
            #pragma unroll
            for (int jn = 0; jn < 4; ++jn)
                if (jn < nvalid) ksh[lane * N_ + start + 4 * g + jn] = oacc[g][jn];
        }
    }
    __syncthreads();
    {   // coalesced store of O into the q region (this block's own q rows)
        float4* dst = reinterpret_cast<float4*>(og + hb);
        const float4* src = reinterpret_cast<const float4*>(ksh);
        for (int e = t; e < 3136; e += 1024) dst[e] = src[e];
    }
}

extern "C" void kernel_launch(void* const* d_in, const int* in_sizes, int n_in,
                              void* d_out, int out_size, void* d_ws, size_t ws_size,
                              hipStream_t stream) {
    const float* x      = (const float*)d_in[0];
    const float* qkv_w  = (const float*)d_in[1];
    const float* qkv_b  = (const float*)d_in[2];
    const float* proj_w = (const float*)d_in[3];
    const float* proj_b = (const float*)d_in[4];
    const float* biases = (const float*)d_in[5];
    const int*   bidx   = (const int*)d_in[6];
    float* out = (float*)d_out;

    // ws: q then v (51.4 MB each). k lives in d_out until proj overwrites it.
    float* qws = (float*)d_ws;
    float* vws = qws + (size_t)B_ * BSTRIDE;

    (void)hipFuncSetAttribute(reinterpret_cast<const void*>(attn196),
                              hipFuncAttributeMaxDynamicSharedMemorySize,
                              (HD_ * N_ + N_ * HD_) * 4);

    // qkv GEMM: 1536 rows -> q(ws) / k(d_out) / v(ws)
    gemm32<<<dim3(B_, 48), 256, 0, stream>>>(x, qkv_w, qkv_b, qws, out, vws);
    // attention: reads q/k/v, writes O back over the q region
    attn196<<<dim3(B_, HEADS_), 1024, (HD_ * N_ + N_ * HD_) * 4, stream>>>(
        qws, out, vws, biases, bidx, qws);
    // proj GEMM: 512 rows, reads attn (q region), writes final out
    gemm32<<<dim3(B_, 16), 256, 0, stream>>>(qws, proj_w, proj_b, out, out, out);
}

// Round 4
// 963.345 us; speedup vs baseline: 4.1564x; 2.0998x over previous
//
#include <hip/hip_runtime.h>
#include <hip/hip_bf16.h>
#include <math.h>

#define B_     128
#define DIM_   512
#define HEADS_ 8
#define HD_    64
#define N_     196
#define NP_    224            // padded n for XT/OT (14 tiles of 16; tiles 13 garbage, masked)
#define SCALE_ 0.125f
#define BSTRIDE (DIM_ * N_)   // 100352: per-batch stride of [b][512][196] buffers

typedef unsigned short u16;
typedef unsigned int   u32;
typedef __attribute__((ext_vector_type(8))) short bf16x8;   // 8 bf16 = 4 VGPRs
typedef __attribute__((ext_vector_type(4))) float f32x4;

__device__ __forceinline__ float rdlane(float v, int l) {
    return __int_as_float(__builtin_amdgcn_readlane(__float_as_int(v), l));
}
__device__ __forceinline__ u16 f2bf(float f) {              // RNE fp32->bf16
    u32 u = __float_as_uint(f);
    return (u16)((u + 0x7fffu + ((u >> 16) & 1u)) >> 16);
}
__device__ __forceinline__ float bflo(u32 v) { return __uint_as_float(v << 16); }
__device__ __forceinline__ float bfhi(u32 v) { return __uint_as_float(v & 0xffff0000u); }

// ---------------------------------------------------------------------------
// fp32 -> bf16 elementwise (weights). n4 = element_count/4.
// ---------------------------------------------------------------------------
__global__ __launch_bounds__(256) void cvt_bf(
    const float* __restrict__ src, u16* __restrict__ dst, int n4)
{
    const int i = blockIdx.x * 256 + threadIdx.x;
    if (i < n4) {
        const float4 v = reinterpret_cast<const float4*>(src)[i];
        uint2 o;
        o.x = (u32)f2bf(v.x) | ((u32)f2bf(v.y) << 16);
        o.y = (u32)f2bf(v.z) | ((u32)f2bf(v.w) << 16);
        reinterpret_cast<uint2*>(dst)[i] = o;
    }
}

// ---------------------------------------------------------------------------
// x fp32 [b][512][196] -> XT bf16 [b][224][512] (transpose; pad rows left
// garbage -- every consumer masks n>=196 at the store).
// grid (8 ctile, 4 ntile, 128 b), 256 thr, LDS 64x65 tile.
// ---------------------------------------------------------------------------
__global__ __launch_bounds__(256) void cvt_xT(
    const float* __restrict__ x, u16* __restrict__ XT)
{
    __shared__ float tile[64][65];
    const int t = threadIdx.x;
    const int jj = t & 63, ii = t >> 6;
    const int ct = blockIdx.x, ntb = blockIdx.y, b = blockIdx.z;
    const float* xb = x + ((size_t)b * DIM_ + ct * 64) * N_;
    const int n0 = ntb * 64;
    #pragma unroll
    for (int s = 0; s < 16; ++s) {
        const int i = ii + s * 4;                 // c offset
        const int n = n0 + jj;
        tile[i][jj] = (n < N_) ? xb[(size_t)i * N_ + n] : 0.f;
    }
    __syncthreads();
    u16* ot = XT + (size_t)b * NP_ * DIM_ + ct * 64;
    #pragma unroll
    for (int s = 0; s < 16; ++s) {
        const int nn = n0 + ii + s * 4;           // n row
        if (nn < N_) ot[(size_t)nn * DIM_ + jj] = f2bf(tile[jj][ii + s * 4]);
    }
}

// ---------------------------------------------------------------------------
// bf16 MFMA GEMM: out[r][n] = sum_c W[r][c] * XT[n][c] + bias[r].
// grid (mtiles, B). Block = 32 rows, 4 waves: wave = (osub 16 rows) x (n-half:
// tiles 0-6 / 7-13). acc = 7 frags = 28 VGPRs; NO LDS, NO barriers.
// A[m=lane&15][k=quad*8+j] from W rows; B symmetric from XT rows (16B loads).
// C/D: col=lane&15, row=quad*4+reg (m89-verified). waves_per_eu(4,4): cap 128,
// no occupancy-chasing squeeze (r2/r3 spill post-mortem).
// ---------------------------------------------------------------------------
template<bool OUT_BF16>
__global__ __attribute__((amdgpu_waves_per_eu(4, 4)))
__launch_bounds__(256) void mfma_gemm(
    const u16* __restrict__ XT, const u16* __restrict__ W,
    const float* __restrict__ bias,
    u16* __restrict__ o_q, u16* __restrict__ o_k, u16* __restrict__ o_v,
    float* __restrict__ o_f)
{
    const int t = threadIdx.x;
    const int wave = t >> 6, lane = t & 63;
    const int mt = blockIdx.x, b = blockIdx.y;
    const int m = lane & 15, quad = lane >> 4;
    const int og0 = mt * 32 + (wave & 1) * 16;    // wave's 16 global out rows
    const int nt0 = (wave >> 1) * 7;              // n-tile base: 0 or 7

    const u16* wp = W + (size_t)(og0 + m) * DIM_ + quad * 8;
    const u16* xp = XT + ((size_t)b * NP_ + (nt0 * 16 + m)) * DIM_ + quad * 8;

    f32x4 acc[7];
    const f32x4 z4 = {0.f, 0.f, 0.f, 0.f};
    #pragma unroll
    for (int nt = 0; nt < 7; ++nt) acc[nt] = z4;

    #pragma unroll 4
    for (int kc = 0; kc < 16; ++kc) {
        const bf16x8 af = *reinterpret_cast<const bf16x8*>(wp + kc * 32);
        #pragma unroll
        for (int nt = 0; nt < 7; ++nt) {
            const bf16x8 bf = *reinterpret_cast<const bf16x8*>(xp + (size_t)nt * 16 * DIM_ + kc * 32);
            acc[nt] = __builtin_amdgcn_mfma_f32_16x16x32_bf16(af, bf, acc[nt], 0, 0, 0);
        }
    }

    const int r0 = og0 + quad * 4;                // global row of acc[.][0]
    float bb[4];
    #pragma unroll
    for (int r = 0; r < 4; ++r) bb[r] = bias[r0 + r];

    if (OUT_BF16) {                               // qkv: split q/k/v, bf16 out
        const int part = og0 >> 9;                // uniform per block
        u16* ob = (part == 0 ? o_q : (part == 1 ? o_k : o_v))
                  + (size_t)b * BSTRIDE + (size_t)(r0 & (DIM_ - 1)) * N_;
        #pragma unroll
        for (int nt = 0; nt < 7; ++nt) {
            const int n = (nt0 + nt) * 16 + m;
            if (n < N_) {
                #pragma unroll
                for (int r = 0; r < 4; ++r) ob[r * N_ + n] = f2bf(acc[nt][r] + bb[r]);
            }
        }
    } else {                                      // proj: final fp32 out
        float* ob = o_f + (size_t)b * BSTRIDE + (size_t)r0 * N_;
        #pragma unroll
        for (int nt = 0; nt < 7; ++nt) {
            const int n = (nt0 + nt) * 16 + m;
            if (n < N_) {
                #pragma unroll
                for (int r = 0; r < 4; ++r) ob[r * N_ + n] = acc[nt][r] + bb[r];
            }
        }
    }
}

// ---------------------------------------------------------------------------
// Attention per (b,h), fp32 math (proven r2/r3), bf16 in/out.
// 1024 thr. LDS = k[64][196] + v^T[196][64] fp32 (100 KB). Epilogue writes
// O transposed as bf16 into OT[b][224][512] (the dead XT buffer) for proj.
// ---------------------------------------------------------------------------
__global__ __attribute__((amdgpu_waves_per_eu(4, 4)))
__launch_bounds__(1024) void attn196(
    const u16* __restrict__ qg, const u16* __restrict__ kg,
    const u16* __restrict__ vg, const float* __restrict__ biases,
    const int* __restrict__ bidx, u16* __restrict__ OT)
{
    extern __shared__ float lds2[];
    float* ksh = lds2;             // k [d][196]; reused as O [d][196] at the end
    float* vt  = lds2 + HD_ * N_;  // v^T [m][64], xor bank swizzle
    const int t = threadIdx.x;
    const int wave = t >> 6, lane = t & 63;
    const int b = blockIdx.x, h = blockIdx.y;
    const size_t hb = ((size_t)b * DIM_ + (size_t)h * HD_) * N_;

    {   // stage k and v (bf16 -> fp32), coalesced 8B reads
        const uint2* ks = reinterpret_cast<const uint2*>(kg + hb);
        for (int e = t; e < 3136; e += 1024) {
            const uint2 kv = ks[e];
            float4 f;
            f.x = bflo(kv.x); f.y = bfhi(kv.x); f.z = bflo(kv.y); f.w = bfhi(kv.y);
            reinterpret_cast<float4*>(ksh)[e] = f;
        }
        const uint2* vs = reinterpret_cast<const uint2*>(vg + hb);
        for (int e = t; e < 3136; e += 1024) {
            const uint2 vv = vs[e];
            const int d = e / 49, m0 = 4 * (e % 49);
            float f[4] = {bflo(vv.x), bfhi(vv.x), bflo(vv.y), bfhi(vv.y)};
            #pragma unroll
            for (int i = 0; i < 4; ++i) {
                const int mm = m0 + i;
                vt[mm * HD_ + (d ^ (mm & 31))] = f[i];
            }
        }
    }
    __syncthreads();

    const int start = (wave < 4) ? 13 * wave : 52 + 12 * (wave - 4);
    const int nrows = (wave < 4) ? 13 : 12;
    const int G = (nrows + 3) >> 2;
    const int mc = (lane <= 48) ? 4 * lane : 192;
    const bool mok = (lane <= 48);
    const float* bh = biases + h * N_;
    const u16* qp = qg + hb + (size_t)lane * N_;  // q row d = lane

    float oacc[4][4];
    #pragma unroll
    for (int g = 0; g < 4; ++g)
        #pragma unroll
        for (int j = 0; j < 4; ++j) oacc[g][j] = 0.f;

    #pragma unroll
    for (int g = 0; g < 4; ++g) {
        if (g < G) {
            const int nvalid = (nrows - 4 * g >= 4) ? 4 : (nrows - 4 * g);
            int ncol[4];
            #pragma unroll
            for (int jn = 0; jn < 4; ++jn) ncol[jn] = start + 4 * g + ((jn < nvalid) ? jn : 0);
            float q4[4];
            #pragma unroll
            for (int jn = 0; jn < 4; ++jn) q4[jn] = bflo((u32)qp[ncol[jn]]);

            float4 s4[4];
            #pragma unroll
            for (int jn = 0; jn < 4; ++jn) s4[jn] = make_float4(0.f, 0.f, 0.f, 0.f);
            #pragma unroll 4
            for (int d = 0; d < 64; ++d) {
                const float4 kv = *reinterpret_cast<const float4*>(&ksh[d * N_ + mc]);
                #pragma unroll
                for (int jn = 0; jn < 4; ++jn) {
                    const float qv = rdlane(q4[jn], d);
                    s4[jn].x = fmaf(qv, kv.x, s4[jn].x);
                    s4[jn].y = fmaf(qv, kv.y, s4[jn].y);
                    s4[jn].z = fmaf(qv, kv.z, s4[jn].z);
                    s4[jn].w = fmaf(qv, kv.w, s4[jn].w);
                }
            }
            float pvA[4][4];
            #pragma unroll
            for (int jn = 0; jn < 4; ++jn) {
                const int4 iv = *reinterpret_cast<const int4*>(&bidx[(size_t)ncol[jn] * N_ + mc]);
                const int* ivp = reinterpret_cast<const int*>(&iv);
                const float* sp = reinterpret_cast<const float*>(&s4[jn]);
                float sv[4]; float mx = -INFINITY;
                #pragma unroll
                for (int jj = 0; jj < 4; ++jj) {
                    const float vv = mok ? fmaf(sp[jj], SCALE_, bh[ivp[jj]]) : -INFINITY;
                    sv[jj] = vv; mx = fmaxf(mx, vv);
                }
                #pragma unroll
                for (int off = 1; off < 64; off <<= 1) mx = fmaxf(mx, __shfl_xor(mx, off, 64));
                float sum = 0.f;
                #pragma unroll
                for (int jj = 0; jj < 4; ++jj) { const float e = __expf(sv[jj] - mx); sv[jj] = e; sum += e; }
                #pragma unroll
                for (int off = 1; off < 64; off <<= 1) sum += __shfl_xor(sum, off, 64);
                const float inv = 1.f / sum;
                #pragma unroll
                for (int jj = 0; jj < 4; ++jj) pvA[jn][jj] = sv[jj] * inv;
            }
            for (int s = 0; s < 49; ++s) {
                const int m0 = 4 * s;
                float vvm[4];
                #pragma unroll
                for (int mm = 0; mm < 4; ++mm)
                    vvm[mm] = vt[(m0 + mm) * HD_ + (lane ^ ((m0 + mm) & 31))];
                #pragma unroll
                for (int jn = 0; jn < 4; ++jn)
                    #pragma unroll
                    for (int mm = 0; mm < 4; ++mm)
                        oacc[g][jn] = fmaf(rdlane(pvA[jn][mm], s), vvm[mm], oacc[g][jn]);
            }
        }
    }
    __syncthreads();
    #pragma unroll
    for (int g = 0; g < 4; ++g) {
        if (g < G) {
            const int nvalid = (nrows - 4 * g >= 4) ? 4 : (nrows - 4 * g);
            #pragma unroll
            for (int jn = 0; jn < 4; ++jn)
                if (jn < nvalid) ksh[lane * N_ + start + 4 * g + jn] = oacc[g][jn];
        }
    }
    __syncthreads();
    {   // O[d][n] -> OT[b][n][h*64+d] bf16 (proj B-operand); 128B/wave stores
        u16* otb = OT + (size_t)b * NP_ * DIM_ + (size_t)h * HD_;
        for (int n = wave; n < N_; n += 16)
            otb[(size_t)n * DIM_ + lane] = f2bf(ksh[lane * N_ + n]);
    }
}

extern "C" void kernel_launch(void* const* d_in, const int* in_sizes, int n_in,
                              void* d_out, int out_size, void* d_ws, size_t ws_size,
                              hipStream_t stream) {
    const float* x      = (const float*)d_in[0];
    const float* qkv_w  = (const float*)d_in[1];
    const float* qkv_b  = (const float*)d_in[2];
    const float* proj_w = (const float*)d_in[3];
    const float* proj_b = (const float*)d_in[4];
    const float* biases = (const float*)d_in[5];
    const int*   bidx   = (const int*)d_in[6];
    float* out = (float*)d_out;

    // ws layout (79 MB total; proven budget 103 MB):
    char* w = (char*)d_ws;
    u16* XT  = (u16*)w; w += (size_t)B_ * NP_ * DIM_ * 2;      // 29.4 MB, reused as OT
    u16* qus = (u16*)w; w += (size_t)B_ * BSTRIDE * 2;         // 25.7 MB
    u16* vus = (u16*)w; w += (size_t)B_ * BSTRIDE * 2;         // 25.7 MB
    u16* wq  = (u16*)w; w += (size_t)3 * DIM_ * DIM_ * 2;      // 1.6 MB
    u16* wpj = (u16*)w;                                        // 0.5 MB
    u16* kus = (u16*)d_out;                                    // k parked in d_out

    const int attn_lds = (HD_ * N_ + N_ * HD_) * 4;            // 100,352 B
    (void)hipFuncSetAttribute(reinterpret_cast<const void*>(attn196),
                              hipFuncAttributeMaxDynamicSharedMemorySize, attn_lds);

    cvt_bf<<<(3 * DIM_ * DIM_ / 4 + 255) / 256, 256, 0, stream>>>(qkv_w, wq, 3 * DIM_ * DIM_ / 4);
    cvt_bf<<<(DIM_ * DIM_ / 4 + 255) / 256, 256, 0, stream>>>(proj_w, wpj, DIM_ * DIM_ / 4);
    cvt_xT<<<dim3(8, 4, B_), 256, 0, stream>>>(x, XT);
    mfma_gemm<true><<<dim3(48, B_), 256, 0, stream>>>(XT, wq, qkv_b, qus, kus, vus, nullptr);
    attn196<<<dim3(B_, HEADS_), 1024, attn_lds, stream>>>(qus, kus, vus, biases, bidx, XT);
    mfma_gemm<false><<<dim3(16, B_), 256, 0, stream>>>(XT, wpj, proj_b, nullptr, nullptr, nullptr, out);
}

// Round 5
// 832.595 us; speedup vs baseline: 4.8091x; 1.1570x over previous
//
#include <hip/hip_runtime.h>
#include <hip/hip_bf16.h>
#include <math.h>

#define B_     128
#define DIM_   512
#define HEADS_ 8
#define HD_    64
#define N_     196
#define NP_    224            // padded n (14 tiles of 16) for XT/OT and attention m-dim
#define NROW_  208            // padded n rows (13 tiles of 16) for EB / qT
#define SCALE_ 0.125f
#define BSTRIDE (DIM_ * N_)

typedef unsigned short u16;
typedef unsigned int   u32;
typedef __attribute__((ext_vector_type(8))) short bf16x8;   // 8 bf16 = 4 VGPRs
typedef __attribute__((ext_vector_type(4))) float f32x4;

__device__ __forceinline__ u16 f2bf(float f) {              // RNE fp32->bf16 (NaN-safe)
    u32 u = __float_as_uint(f);
    return (u16)((u + 0x7fffu + ((u >> 16) & 1u)) >> 16);
}

// ---------------------------------------------------------------------------
// fp32 -> bf16 elementwise (weights). n4 = element_count/4.
// ---------------------------------------------------------------------------
__global__ __launch_bounds__(256) void cvt_bf(
    const float* __restrict__ src, u16* __restrict__ dst, int n4)
{
    const int i = blockIdx.x * 256 + threadIdx.x;
    if (i < n4) {
        const float4 v = reinterpret_cast<const float4*>(src)[i];
        uint2 o;
        o.x = (u32)f2bf(v.x) | ((u32)f2bf(v.y) << 16);
        o.y = (u32)f2bf(v.z) | ((u32)f2bf(v.w) << 16);
        reinterpret_cast<uint2*>(dst)[i] = o;
    }
}

// ---------------------------------------------------------------------------
// x fp32 [b][512][196] -> XT bf16 [b][224][512] (transpose; pad rows garbage,
// masked by every consumer at the store).
// ---------------------------------------------------------------------------
__global__ __launch_bounds__(256) void cvt_xT(
    const float* __restrict__ x, u16* __restrict__ XT)
{
    __shared__ float tile[64][65];
    const int t = threadIdx.x;
    const int jj = t & 63, ii = t >> 6;
    const int ct = blockIdx.x, ntb = blockIdx.y, b = blockIdx.z;
    const float* xb = x + ((size_t)b * DIM_ + ct * 64) * N_;
    const int n0 = ntb * 64;
    #pragma unroll
    for (int s = 0; s < 16; ++s) {
        const int i = ii + s * 4;
        const int n = n0 + jj;
        tile[i][jj] = (n < N_) ? xb[(size_t)i * N_ + n] : 0.f;
    }
    __syncthreads();
    u16* ot = XT + (size_t)b * NP_ * DIM_ + ct * 64;
    #pragma unroll
    for (int s = 0; s < 16; ++s) {
        const int nn = n0 + ii + s * 4;
        if (nn < N_) ot[(size_t)nn * DIM_ + jj] = f2bf(tile[jj][ii + s * 4]);
    }
}

// ---------------------------------------------------------------------------
// EB[h][208][224] = exp(bias[h][bidx[n][m]]) for n,m<196 else 0.
// The 0-pad kills every padded-m contribution in attention (P=exp*0=0), so
// the padded regions of kT/v never need zeroing (poison is finite -> exp
// bounded -> times 0). softmax shift-invariance makes exp(bias) exact.
// ---------------------------------------------------------------------------
__global__ __launch_bounds__(256) void mk_eb(
    const float* __restrict__ biases, const int* __restrict__ bidx,
    float* __restrict__ EB)
{
    const int n = blockIdx.x, h = blockIdx.y;
    const int m = threadIdx.x;
    if (m < NP_) {
        float v = 0.f;
        if (n < N_ && m < N_) v = __expf(biases[h * N_ + bidx[n * N_ + m]]);
        EB[((size_t)h * NROW_ + n) * NP_ + m] = v;
    }
}

// ---------------------------------------------------------------------------
// bf16 MFMA GEMM: out[r][n] = sum_c W[r][c] * XT[n][c] + bias[r].
// Block = 32 rows, 4 waves = (16-row half) x (n-tile half 0-6 / 7-13).
// acc = 7 frags = 28 VGPRs; NO LDS, NO barriers. C/D: col=lane&15 (B-row),
// row=quad*4+reg (A-row), m89-verified (passed r4 bench).
// qkv epilogue emits attention layouts: qT/kT[b][h][n][64] (8B packed
// stores), v[b][h][d][224] (2B stores). proj emits final fp32 [b][512][196].
// ---------------------------------------------------------------------------
template<bool OUT_BF16>
__global__ __attribute__((amdgpu_waves_per_eu(4, 4)))
__launch_bounds__(256) void mfma_gemm(
    const u16* __restrict__ XT, const u16* __restrict__ W,
    const float* __restrict__ bias,
    u16* __restrict__ o_q, u16* __restrict__ o_k, u16* __restrict__ o_v,
    float* __restrict__ o_f)
{
    const int t = threadIdx.x;
    const int wave = t >> 6, lane = t & 63;
    const int mt = blockIdx.x, b = blockIdx.y;
    const int m16 = lane & 15, quad = lane >> 4;
    const int og0 = mt * 32 + (wave & 1) * 16;    // wave's 16 global out rows
    const int nt0 = (wave >> 1) * 7;              // n-tile base: 0 or 7

    const u16* wp = W + (size_t)(og0 + m16) * DIM_ + quad * 8;
    const u16* xp = XT + ((size_t)b * NP_ + (nt0 * 16 + m16)) * DIM_ + quad * 8;

    f32x4 acc[7];
    const f32x4 z4 = {0.f, 0.f, 0.f, 0.f};
    #pragma unroll
    for (int nt = 0; nt < 7; ++nt) acc[nt] = z4;

    #pragma unroll 4
    for (int kc = 0; kc < 16; ++kc) {
        const bf16x8 af = *reinterpret_cast<const bf16x8*>(wp + kc * 32);
        #pragma unroll
        for (int nt = 0; nt < 7; ++nt) {
            const bf16x8 bf = *reinterpret_cast<const bf16x8*>(xp + (size_t)nt * 16 * DIM_ + kc * 32);
            acc[nt] = __builtin_amdgcn_mfma_f32_16x16x32_bf16(af, bf, acc[nt], 0, 0, 0);
        }
    }

    const int r0 = og0 + quad * 4;                // global row of acc[.][0]
    float bb[4];
    #pragma unroll
    for (int r = 0; r < 4; ++r) bb[r] = bias[r0 + r];

    if (OUT_BF16) {
        const int part = og0 >> 9;                // 0=q 1=k 2=v (uniform/block)
        const int o = og0 & 511;
        const int h = o >> 6;                     // uniform per wave
        const int d0 = (o & 63) + quad * 4;       // 4 consecutive d per lane
        if (part < 2) {                           // q,k -> [b][h][n][64], 8B stores
            u16* qkb = (part == 0 ? o_q : o_k) + (((size_t)b * HEADS_ + h) * NP_) * HD_ + d0;
            #pragma unroll
            for (int nt = 0; nt < 7; ++nt) {
                const int n = (nt0 + nt) * 16 + m16;
                if (n < N_) {
                    uint2 pk;
                    pk.x = (u32)f2bf(acc[nt][0] + bb[0]) | ((u32)f2bf(acc[nt][1] + bb[1]) << 16);
                    pk.y = (u32)f2bf(acc[nt][2] + bb[2]) | ((u32)f2bf(acc[nt][3] + bb[3]) << 16);
                    *reinterpret_cast<uint2*>(qkb + (size_t)n * HD_) = pk;
                }
            }
        } else {                                  // v -> [b][h][d][224], 2B stores
            u16* vb = o_v + (((size_t)b * HEADS_ + h) * HD_ + d0) * NP_;
            #pragma unroll
            for (int nt = 0; nt < 7; ++nt) {
                const int n = (nt0 + nt) * 16 + m16;
                if (n < N_) {
                    #pragma unroll
                    for (int r = 0; r < 4; ++r) vb[r * NP_ + n] = f2bf(acc[nt][r] + bb[r]);
                }
            }
        }
    } else {                                      // proj: final fp32 out
        float* ob = o_f + (size_t)b * BSTRIDE + (size_t)r0 * N_;
        #pragma unroll
        for (int nt = 0; nt < 7; ++nt) {
            const int n = (nt0 + nt) * 16 + m16;
            if (n < N_) {
                #pragma unroll
                for (int r = 0; r < 4; ++r) ob[r * N_ + n] = acc[nt][r] + bb[r];
            }
        }
    }
}

// ---------------------------------------------------------------------------
// MFMA attention per (b,h). 4 waves, ZERO barriers, LDS = per-wave P only.
// Wave handles n-tiles {wave, wave+4, ...} (13 tiles of 16 rows).
//   QK^T: A=qT[n][d] (global), B=kT[m][d] (global, 28KB slice -> L1-hot),
//         2 k-steps x 14 m-tiles -> S in 14 C-frags (56 VGPRs).
//   softmax in C-layout: row n = quad*4+reg over 16 lanes -> shfl_xor(1,2,4,8);
//         p = exp(s*scale - mx) * EB[h][n][m]  (EB = exp(bias), 0 at pads).
//   P -> per-wave LDS [16][232] bf16 (stride pad vs bank conflicts), no barrier
//         (same-wave RAW, waitcnt only).
//   PV:  A=P (LDS b128), B=v[d][m] (global, L1-hot), 7 k-steps x 4 d-tiles.
//   O^T[n][h*64+d] bf16 -> OT (proj B-operand layout), n<196 masked.
// Masked rows (n>=196): garbage-but-finite -> 0-sum softmax -> NaN P row ->
// NaN confined to its own output rows -> never stored.
// ---------------------------------------------------------------------------
__global__ __attribute__((amdgpu_waves_per_eu(4, 4)))
__launch_bounds__(256) void attn_mfma(
    const u16* __restrict__ qT, const u16* __restrict__ kT,
    const u16* __restrict__ vS, const float* __restrict__ EB,
    u16* __restrict__ OT)
{
    __shared__ u16 P[4][16 * 232];
    const int t = threadIdx.x;
    const int wave = t >> 6, lane = t & 63;
    const int m16 = lane & 15, quad = lane >> 4;
    const int b = blockIdx.x, h = blockIdx.y;
    const u16* qTb = qT + ((size_t)b * HEADS_ + h) * (NP_ * HD_);
    const u16* kTb = kT + ((size_t)b * HEADS_ + h) * (NP_ * HD_);
    const u16* vb  = vS + ((size_t)b * HEADS_ + h) * (HD_ * NP_);
    const float* ebh = EB + (size_t)h * NROW_ * NP_;
    u16* Pw = P[wave];
    u16* otb = OT + (size_t)b * NP_ * DIM_ + h * HD_;
    const f32x4 z4 = {0.f, 0.f, 0.f, 0.f};

    for (int nt = wave; nt < 13; nt += 4) {
        // ---- S = qT . kT^T (k = d, 64) ----
        f32x4 s[14];
        #pragma unroll
        for (int mt = 0; mt < 14; ++mt) s[mt] = z4;
        #pragma unroll
        for (int ks = 0; ks < 2; ++ks) {
            const bf16x8 a = *reinterpret_cast<const bf16x8*>(
                qTb + (size_t)(nt * 16 + m16) * HD_ + ks * 32 + quad * 8);
            #pragma unroll
            for (int mtile = 0; mtile < 14; ++mtile) {
                const bf16x8 bf = *reinterpret_cast<const bf16x8*>(
                    kTb + (size_t)(mtile * 16 + m16) * HD_ + ks * 32 + quad * 8);
                s[mtile] = __builtin_amdgcn_mfma_f32_16x16x32_bf16(a, bf, s[mtile], 0, 0, 0);
            }
        }
        // ---- softmax over m (row n = nt*16 + quad*4 + r) ----
        float mx[4] = {-INFINITY, -INFINITY, -INFINITY, -INFINITY};
        #pragma unroll
        for (int mt = 0; mt < 14; ++mt)
            #pragma unroll
            for (int r = 0; r < 4; ++r) mx[r] = fmaxf(mx[r], s[mt][r]);
        #pragma unroll
        for (int off = 1; off < 16; off <<= 1)
            #pragma unroll
            for (int r = 0; r < 4; ++r) mx[r] = fmaxf(mx[r], __shfl_xor(mx[r], off, 64));
        #pragma unroll
        for (int r = 0; r < 4; ++r) mx[r] *= SCALE_;

        const float* ebn = ebh + (size_t)(nt * 16 + quad * 4) * NP_ + m16;
        float sum[4] = {0.f, 0.f, 0.f, 0.f};
        #pragma unroll
        for (int mt = 0; mt < 14; ++mt) {
            #pragma unroll
            for (int r = 0; r < 4; ++r) {
                const float e = __expf(fmaf(s[mt][r], SCALE_, -mx[r])) * ebn[(size_t)r * NP_ + mt * 16];
                s[mt][r] = e;
                sum[r] += e;
            }
        }
        #pragma unroll
        for (int off = 1; off < 16; off <<= 1)
            #pragma unroll
            for (int r = 0; r < 4; ++r) sum[r] += __shfl_xor(sum[r], off, 64);
        float inv[4];
        #pragma unroll
        for (int r = 0; r < 4; ++r) inv[r] = 1.f / sum[r];

        #pragma unroll
        for (int mt = 0; mt < 14; ++mt)
            #pragma unroll
            for (int r = 0; r < 4; ++r)
                Pw[(quad * 4 + r) * 232 + mt * 16 + m16] = f2bf(s[mt][r] * inv[r]);

        // ---- O^T = P . v^T (k = m, 224) ----
        f32x4 o[4];
        #pragma unroll
        for (int dt = 0; dt < 4; ++dt) o[dt] = z4;
        #pragma unroll
        for (int ks = 0; ks < 7; ++ks) {
            const bf16x8 a = *reinterpret_cast<const bf16x8*>(Pw + m16 * 232 + ks * 32 + quad * 8);
            #pragma unroll
            for (int dt = 0; dt < 4; ++dt) {
                const bf16x8 bf = *reinterpret_cast<const bf16x8*>(
                    vb + (size_t)(dt * 16 + m16) * NP_ + ks * 32 + quad * 8);
                o[dt] = __builtin_amdgcn_mfma_f32_16x16x32_bf16(a, bf, o[dt], 0, 0, 0);
            }
        }
        // ---- store O^T rows (col d = dt*16+m16, row n = quad*4+r) ----
        #pragma unroll
        for (int r = 0; r < 4; ++r) {
            const int n = nt * 16 + quad * 4 + r;
            if (n < N_) {
                #pragma unroll
                for (int dt = 0; dt < 4; ++dt)
                    otb[(size_t)n * DIM_ + dt * 16 + m16] = f2bf(o[dt][r]);
            }
        }
    }
}

extern "C" void kernel_launch(void* const* d_in, const int* in_sizes, int n_in,
                              void* d_out, int out_size, void* d_ws, size_t ws_size,
                              hipStream_t stream) {
    const float* x      = (const float*)d_in[0];
    const float* qkv_w  = (const float*)d_in[1];
    const float* qkv_b  = (const float*)d_in[2];
    const float* proj_w = (const float*)d_in[3];
    const float* proj_b = (const float*)d_in[4];
    const float* biases = (const float*)d_in[5];
    const int*   bidx   = (const int*)d_in[6];
    float* out = (float*)d_out;

    // ws layout (~92 MB; 103 MB proven safe in r2/r3):
    char* w = (char*)d_ws;
    u16* XT  = (u16*)w; w += (size_t)B_ * NP_ * DIM_ * 2;            // 29.4 MB (reused as OT)
    u16* qTw = (u16*)w; w += (size_t)B_ * HEADS_ * NP_ * HD_ * 2;    // 29.4 MB
    u16* vSw = (u16*)w; w += (size_t)B_ * HEADS_ * HD_ * NP_ * 2;    // 29.4 MB
    float* EB = (float*)w; w += (size_t)HEADS_ * NROW_ * NP_ * 4;    // 1.5 MB
    u16* wq  = (u16*)w; w += (size_t)3 * DIM_ * DIM_ * 2;            // 1.6 MB
    u16* wpj = (u16*)w;                                              // 0.5 MB
    u16* kTw = (u16*)d_out;                                          // kT parked in d_out

    cvt_bf<<<(3 * DIM_ * DIM_ / 4 + 255) / 256, 256, 0, stream>>>(qkv_w, wq, 3 * DIM_ * DIM_ / 4);
    cvt_bf<<<(DIM_ * DIM_ / 4 + 255) / 256, 256, 0, stream>>>(proj_w, wpj, DIM_ * DIM_ / 4);
    cvt_xT<<<dim3(8, 4, B_), 256, 0, stream>>>(x, XT);
    mk_eb<<<dim3(NROW_, HEADS_), 256, 0, stream>>>(biases, bidx, EB);
    mfma_gemm<true><<<dim3(48, B_), 256, 0, stream>>>(XT, wq, qkv_b, qTw, kTw, vSw, nullptr);
    attn_mfma<<<dim3(B_, HEADS_), 256, 0, stream>>>(qTw, kTw, vSw, EB, XT);
    mfma_gemm<false><<<dim3(16, B_), 256, 0, stream>>>(XT, wpj, proj_b, nullptr, nullptr, nullptr, out);
}

// Round 6
// 497.559 us; speedup vs baseline: 8.0474x; 1.6734x over previous
//
#include <hip/hip_runtime.h>
#include <hip/hip_bf16.h>
#include <math.h>

#define B_     128
#define DIM_   512
#define HEADS_ 8
#define HD_    64
#define N_     196
#define NP_    224            // padded n (14 tiles of 16)
#define NROW_  208            // padded n rows (13 tiles of 16) for EB
#define SCALE_ 0.125f
#define BSTRIDE (DIM_ * N_)
#define J_     (B_ * NP_)     // 28672 GEMM columns (b*224+n)

typedef unsigned short u16;
typedef unsigned int   u32;
typedef __attribute__((ext_vector_type(8))) short bf16x8;   // 8 bf16 = 4 VGPRs
typedef __attribute__((ext_vector_type(4))) float f32x4;

__device__ __forceinline__ u16 f2bf(float f) {              // RNE fp32->bf16
    u32 u = __float_as_uint(f);
    return (u16)((u + 0x7fffu + ((u >> 16) & 1u)) >> 16);
}
__device__ __forceinline__ void gload_lds16(const u16* g, u16* l) {
    // async global->LDS, 16B/lane; LDS dest = wave-uniform base + lane*16
    __builtin_amdgcn_global_load_lds(
        (const __attribute__((address_space(1))) void*)g,
        (__attribute__((address_space(3))) void*)l, 16, 0, 0);
}

// ---------------------------------------------------------------------------
// fp32 -> bf16 elementwise (weights).
// ---------------------------------------------------------------------------
__global__ __launch_bounds__(256) void cvt_bf(
    const float* __restrict__ src, u16* __restrict__ dst, int n4)
{
    const int i = blockIdx.x * 256 + threadIdx.x;
    if (i < n4) {
        const float4 v = reinterpret_cast<const float4*>(src)[i];
        uint2 o;
        o.x = (u32)f2bf(v.x) | ((u32)f2bf(v.y) << 16);
        o.y = (u32)f2bf(v.z) | ((u32)f2bf(v.w) << 16);
        reinterpret_cast<uint2*>(dst)[i] = o;
    }
}

// ---------------------------------------------------------------------------
// x fp32 [b][512][196] -> XT bf16 [b][224][512] (pad rows garbage, masked
// downstream: EB=0 for m>=196, OT/out stores guarded for n>=196).
// ---------------------------------------------------------------------------
__global__ __launch_bounds__(256) void cvt_xT(
    const float* __restrict__ x, u16* __restrict__ XT)
{
    __shared__ float tile[64][65];
    const int t = threadIdx.x;
    const int jj = t & 63, ii = t >> 6;
    const int ct = blockIdx.x, ntb = blockIdx.y, b = blockIdx.z;
    const float* xb = x + ((size_t)b * DIM_ + ct * 64) * N_;
    const int n0 = ntb * 64;
    #pragma unroll
    for (int s = 0; s < 16; ++s) {
        const int i = ii + s * 4;
        const int n = n0 + jj;
        tile[i][jj] = (n < N_) ? xb[(size_t)i * N_ + n] : 0.f;
    }
    __syncthreads();
    u16* ot = XT + (size_t)b * NP_ * DIM_ + ct * 64;
    #pragma unroll
    for (int s = 0; s < 16; ++s) {
        const int nn = n0 + ii + s * 4;
        if (nn < N_) ot[(size_t)nn * DIM_ + jj] = f2bf(tile[jj][ii + s * 4]);
    }
}

// ---------------------------------------------------------------------------
// EB[h][208][224] = exp(bias[h][bidx[n][m]]) for n,m<196 else 0.
// ---------------------------------------------------------------------------
__global__ __launch_bounds__(256) void mk_eb(
    const float* __restrict__ biases, const int* __restrict__ bidx,
    float* __restrict__ EB)
{
    const int n = blockIdx.x, h = blockIdx.y;
    const int m = threadIdx.x;
    if (m < NP_) {
        float v = 0.f;
        if (n < N_ && m < N_) v = __expf(biases[h * N_ + bidx[n * N_ + m]]);
        EB[((size_t)h * NROW_ + n) * NP_ + m] = v;
    }
}

// ---------------------------------------------------------------------------
// m97-style 128x128 MFMA GEMM: C[M][28672] = W[M][512] . XT[28672][512]^T.
// grid (224 j-tiles, M/128 m-tiles), 256 thr = 2x2 waves, wave = 64x64
// (4x4 frags 16x16x32, acc 64 VGPR). BK=32: two 8 KB LDS tiles staged by
// global_load_lds width=16 (4 calls/wave/iter), 16 K-iters, 2-barrier loop.
// LDS slot map slot(row,chunk)=row*4+(chunk^((row>>1)&3)) via SOURCE chunk
// permutation (dest must be lane-contiguous) -> frag ds_read_b128 is 2-way
// bank-aliased = free (m136). r3 lesson: no waves_per_eu attribute.
// Epilogue QKV: qT/kT[b][h][n<=224][64] (8B stores), vS[b][h][d][224];
// pads stored unguarded -- EB=0 masks every pad contribution downstream.
// Epilogue proj: fp32 out[b][512][196], n guarded.
// ---------------------------------------------------------------------------
template<bool QKV>
__global__ __launch_bounds__(256) void gemm128(
    const u16* __restrict__ Bt, const u16* __restrict__ W,
    const float* __restrict__ bias,
    u16* __restrict__ o_q, u16* __restrict__ o_k, u16* __restrict__ o_v,
    float* __restrict__ o_f)
{
    __shared__ u16 As[128 * 32];
    __shared__ u16 Bs[128 * 32];
    const int t = threadIdx.x;
    const int wave = t >> 6, lane = t & 63;
    const int m16 = lane & 15, quad = lane >> 4;
    const int jt = blockIdx.x, mt = blockIdx.y;
    const int m0 = mt * 128, j0 = jt * 128;
    const int wy = wave >> 1, wx = wave & 1;     // wave tile: rows wy*64, cols wx*64

    // staging: call c = wave*2+cc fills slots [c*64, c*64+64); lane's source
    // row = c*16 + (lane>>2), source chunk = (lane&3) ^ ((lane>>3)&3).
    const int srow  = (lane >> 2);               // + c*16
    const int schnk = (lane & 3) ^ ((lane >> 3) & 3);
    const u16* gA = W  + (size_t)(m0 + wave * 32 + srow) * DIM_ + schnk * 8;
    const u16* gB = Bt + (size_t)(j0 + wave * 32 + srow) * DIM_ + schnk * 8;

    // frag read column: col = quad ^ ((m16>>1)&3); u16 offset row*32 + col*8
    const int rcol = (quad ^ ((m16 >> 1) & 3)) * 8;

    f32x4 acc[4][4];
    const f32x4 z4 = {0.f, 0.f, 0.f, 0.f};
    #pragma unroll
    for (int fi = 0; fi < 4; ++fi)
        #pragma unroll
        for (int fj = 0; fj < 4; ++fj) acc[fi][fj] = z4;

    for (int kt = 0; kt < 16; ++kt) {
        __syncthreads();                          // prior iter done reading LDS
        #pragma unroll
        for (int cc = 0; cc < 2; ++cc) {
            const int c = wave * 2 + cc;
            gload_lds16(gA + (size_t)(cc * 16) * DIM_ + kt * 32, As + c * 512);
            gload_lds16(gB + (size_t)(cc * 16) * DIM_ + kt * 32, Bs + c * 512);
        }
        __syncthreads();                          // vmcnt(0) drain -> LDS visible
        bf16x8 af[4], bf[4];
        #pragma unroll
        for (int fi = 0; fi < 4; ++fi)
            af[fi] = *reinterpret_cast<const bf16x8*>(As + (wy * 64 + fi * 16 + m16) * 32 + rcol);
        #pragma unroll
        for (int fj = 0; fj < 4; ++fj)
            bf[fj] = *reinterpret_cast<const bf16x8*>(Bs + (wx * 64 + fj * 16 + m16) * 32 + rcol);
        #pragma unroll
        for (int fi = 0; fi < 4; ++fi)
            #pragma unroll
            for (int fj = 0; fj < 4; ++fj)
                acc[fi][fj] = __builtin_amdgcn_mfma_f32_16x16x32_bf16(af[fi], bf[fj], acc[fi][fj], 0, 0, 0);
    }

    // ---- epilogue ----
    const int mbase = m0 + wy * 64;              // 64-aligned -> part,h wave-uniform
    float bb[4][4];
    #pragma unroll
    for (int fi = 0; fi < 4; ++fi)
        #pragma unroll
        for (int r = 0; r < 4; ++r) bb[fi][r] = bias[mbase + fi * 16 + quad * 4 + r];

    if (QKV) {
        const int part = mbase >> 9;             // 0=q 1=k 2=v
        const int h = (mbase & 511) >> 6;
        #pragma unroll
        for (int fj = 0; fj < 4; ++fj) {
            const int j = j0 + wx * 64 + fj * 16 + m16;
            const u32 b = (u32)j / 224u;
            const int n = j - (int)b * 224;
            if (part < 2) {                      // q,k -> [b][h][n][64], 8B packed
                u16* base = (part == 0 ? o_q : o_k) + (((size_t)b * HEADS_ + h) * NP_ + n) * HD_;
                #pragma unroll
                for (int fi = 0; fi < 4; ++fi) {
                    const int d0 = fi * 16 + quad * 4;
                    uint2 pk;
                    pk.x = (u32)f2bf(acc[fi][fj][0] + bb[fi][0]) | ((u32)f2bf(acc[fi][fj][1] + bb[fi][1]) << 16);
                    pk.y = (u32)f2bf(acc[fi][fj][2] + bb[fi][2]) | ((u32)f2bf(acc[fi][fj][3] + bb[fi][3]) << 16);
                    *reinterpret_cast<uint2*>(base + d0) = pk;
                }
            } else {                             // v -> [b][h][d][224], 2B stores
                u16* vb = o_v + (((size_t)b * HEADS_ + h) * HD_) * NP_ + n;
                #pragma unroll
                for (int fi = 0; fi < 4; ++fi) {
                    const int d0 = fi * 16 + quad * 4;
                    #pragma unroll
                    for (int r = 0; r < 4; ++r)
                        vb[(size_t)(d0 + r) * NP_] = f2bf(acc[fi][fj][r] + bb[fi][r]);
                }
            }
        }
    } else {                                     // proj: fp32 out[b][512][196]
        #pragma unroll
        for (int fj = 0; fj < 4; ++fj) {
            const int j = j0 + wx * 64 + fj * 16 + m16;
            const u32 b = (u32)j / 224u;
            const int n = j - (int)b * 224;
            if (n < N_) {
                float* ob = o_f + (size_t)b * BSTRIDE + n;
                #pragma unroll
                for (int fi = 0; fi < 4; ++fi) {
                    const int r0 = mbase + fi * 16 + quad * 4;
                    #pragma unroll
                    for (int r = 0; r < 4; ++r)
                        ob[(size_t)(r0 + r) * N_] = acc[fi][fj][r] + bb[fi][r];
                }
            }
        }
    }
}

// ---------------------------------------------------------------------------
// MFMA attention per (b,h) -- unchanged from r5 (passed). 4 waves, zero
// barriers, per-wave P in LDS; EB = exp(bias) with 0-pads masks padding.
// ---------------------------------------------------------------------------
__global__ __attribute__((amdgpu_waves_per_eu(4, 4)))
__launch_bounds__(256) void attn_mfma(
    const u16* __restrict__ qT, const u16* __restrict__ kT,
    const u16* __restrict__ vS, const float* __restrict__ EB,
    u16* __restrict__ OT)
{
    __shared__ u16 P[4][16 * 232];
    const int t = threadIdx.x;
    const int wave = t >> 6, lane = t & 63;
    const int m16 = lane & 15, quad = lane >> 4;
    const int b = blockIdx.x, h = blockIdx.y;
    const u16* qTb = qT + ((size_t)b * HEADS_ + h) * (NP_ * HD_);
    const u16* kTb = kT + ((size_t)b * HEADS_ + h) * (NP_ * HD_);
    const u16* vb  = vS + ((size_t)b * HEADS_ + h) * (HD_ * NP_);
    const float* ebh = EB + (size_t)h * NROW_ * NP_;
    u16* Pw = P[wave];
    u16* otb = OT + (size_t)b * NP_ * DIM_ + h * HD_;
    const f32x4 z4 = {0.f, 0.f, 0.f, 0.f};

    for (int nt = wave; nt < 13; nt += 4) {
        f32x4 s[14];
        #pragma unroll
        for (int mt = 0; mt < 14; ++mt) s[mt] = z4;
        #pragma unroll
        for (int ks = 0; ks < 2; ++ks) {
            const bf16x8 a = *reinterpret_cast<const bf16x8*>(
                qTb + (size_t)(nt * 16 + m16) * HD_ + ks * 32 + quad * 8);
            #pragma unroll
            for (int mtile = 0; mtile < 14; ++mtile) {
                const bf16x8 bf = *reinterpret_cast<const bf16x8*>(
                    kTb + (size_t)(mtile * 16 + m16) * HD_ + ks * 32 + quad * 8);
                s[mtile] = __builtin_amdgcn_mfma_f32_16x16x32_bf16(a, bf, s[mtile], 0, 0, 0);
            }
        }
        float mx[4] = {-INFINITY, -INFINITY, -INFINITY, -INFINITY};
        #pragma unroll
        for (int mt = 0; mt < 14; ++mt)
            #pragma unroll
            for (int r = 0; r < 4; ++r) mx[r] = fmaxf(mx[r], s[mt][r]);
        #pragma unroll
        for (int off = 1; off < 16; off <<= 1)
            #pragma unroll
            for (int r = 0; r < 4; ++r) mx[r] = fmaxf(mx[r], __shfl_xor(mx[r], off, 64));
        #pragma unroll
        for (int r = 0; r < 4; ++r) mx[r] *= SCALE_;

        const float* ebn = ebh + (size_t)(nt * 16 + quad * 4) * NP_ + m16;
        float sum[4] = {0.f, 0.f, 0.f, 0.f};
        #pragma unroll
        for (int mt = 0; mt < 14; ++mt) {
            #pragma unroll
            for (int r = 0; r < 4; ++r) {
                const float e = __expf(fmaf(s[mt][r], SCALE_, -mx[r])) * ebn[(size_t)r * NP_ + mt * 16];
                s[mt][r] = e;
                sum[r] += e;
            }
        }
        #pragma unroll
        for (int off = 1; off < 16; off <<= 1)
            #pragma unroll
            for (int r = 0; r < 4; ++r) sum[r] += __shfl_xor(sum[r], off, 64);
        float inv[4];
        #pragma unroll
        for (int r = 0; r < 4; ++r) inv[r] = 1.f / sum[r];

        #pragma unroll
        for (int mt = 0; mt < 14; ++mt)
            #pragma unroll
            for (int r = 0; r < 4; ++r)
                Pw[(quad * 4 + r) * 232 + mt * 16 + m16] = f2bf(s[mt][r] * inv[r]);

        f32x4 o[4];
        #pragma unroll
        for (int dt = 0; dt < 4; ++dt) o[dt] = z4;
        #pragma unroll
        for (int ks = 0; ks < 7; ++ks) {
            const bf16x8 a = *reinterpret_cast<const bf16x8*>(Pw + m16 * 232 + ks * 32 + quad * 8);
            #pragma unroll
            for (int dt = 0; dt < 4; ++dt) {
                const bf16x8 bf = *reinterpret_cast<const bf16x8*>(
                    vb + (size_t)(dt * 16 + m16) * NP_ + ks * 32 + quad * 8);
                o[dt] = __builtin_amdgcn_mfma_f32_16x16x32_bf16(a, bf, o[dt], 0, 0, 0);
            }
        }
        #pragma unroll
        for (int r = 0; r < 4; ++r) {
            const int n = nt * 16 + quad * 4 + r;
            if (n < N_) {
                #pragma unroll
                for (int dt = 0; dt < 4; ++dt)
                    otb[(size_t)n * DIM_ + dt * 16 + m16] = f2bf(o[dt][r]);
            }
        }
    }
}

extern "C" void kernel_launch(void* const* d_in, const int* in_sizes, int n_in,
                              void* d_out, int out_size, void* d_ws, size_t ws_size,
                              hipStream_t stream) {
    const float* x      = (const float*)d_in[0];
    const float* qkv_w  = (const float*)d_in[1];
    const float* qkv_b  = (const float*)d_in[2];
    const float* proj_w = (const float*)d_in[3];
    const float* proj_b = (const float*)d_in[4];
    const float* biases = (const float*)d_in[5];
    const int*   bidx   = (const int*)d_in[6];
    float* out = (float*)d_out;

    // ws layout (~92 MB; 103 MB proven safe):
    char* w = (char*)d_ws;
    u16* XT  = (u16*)w; w += (size_t)B_ * NP_ * DIM_ * 2;            // 29.4 MB (reused as OT)
    u16* qTw = (u16*)w; w += (size_t)B_ * HEADS_ * NP_ * HD_ * 2;    // 29.4 MB
    u16* vSw = (u16*)w; w += (size_t)B_ * HEADS_ * HD_ * NP_ * 2;    // 29.4 MB
    float* EB = (float*)w; w += (size_t)HEADS_ * NROW_ * NP_ * 4;    // 1.5 MB
    u16* wq  = (u16*)w; w += (size_t)3 * DIM_ * DIM_ * 2;            // 1.6 MB
    u16* wpj = (u16*)w;                                              // 0.5 MB
    u16* kTw = (u16*)d_out;                                          // kT parked in d_out

    cvt_bf<<<(3 * DIM_ * DIM_ / 4 + 255) / 256, 256, 0, stream>>>(qkv_w, wq, 3 * DIM_ * DIM_ / 4);
    cvt_bf<<<(DIM_ * DIM_ / 4 + 255) / 256, 256, 0, stream>>>(proj_w, wpj, DIM_ * DIM_ / 4);
    cvt_xT<<<dim3(8, 4, B_), 256, 0, stream>>>(x, XT);
    mk_eb<<<dim3(NROW_, HEADS_), 256, 0, stream>>>(biases, bidx, EB);
    gemm128<true><<<dim3(J_ / 128, 12), 256, 0, stream>>>(XT, wq, qkv_b, qTw, kTw, vSw, nullptr);
    attn_mfma<<<dim3(B_, HEADS_), 256, 0, stream>>>(qTw, kTw, vSw, EB, XT);
    gemm128<false><<<dim3(J_ / 128, 4), 256, 0, stream>>>(XT, wpj, proj_b, nullptr, nullptr, nullptr, out);
}